// Round 6
// baseline (67.500 us; speedup 1.0000x reference)
//
#include <hip/hip_runtime.h>

#define D 128
#define NCLS 3
#define REP 8

typedef float f32x4 __attribute__((ext_vector_type(4)));

// ws layout (floats): [0 .. REP*384-1] per-class sums (REP replicas of {all,c1,c2} x 128),
//                     [REP*384 .. REP*384+REP*2-1] float counts of class1/class2

__global__ __launch_bounds__(256) void class_sum_kernel(
    const float* __restrict__ feat, const int* __restrict__ labels,
    float* __restrict__ sums, float* __restrict__ counts, int N, int fullIters)
{
    __shared__ float s_sum[NCLS * D];   // rows: 0=all, 1=class1, 2=class2
    __shared__ float s_cnt[2];
    const int t = threadIdx.x;

    for (int i = t; i < NCLS * D; i += 256) s_sum[i] = 0.0f;
    if (t < 2) s_cnt[t] = 0.0f;
    __syncthreads();

    const int col4 = t & 31;          // float4 slot within the 128-wide row
    const int rsub = t >> 5;          // 0..7 -> this thread's 4-row group
    const int row0 = blockIdx.x * 32 + rsub * 4;
    const int rowsPerIter = gridDim.x * 32;

    const float* __restrict__ p = feat + (size_t)row0 * D + col4 * 4;
    const int* __restrict__ lp = labels + row0;
    const size_t pStep = (size_t)rowsPerIter * D;

    const f32x4 z = {0.f, 0.f, 0.f, 0.f};
    f32x4 aAll = z, a1 = z, a2 = z;
    float c1f = 0.f, c2f = 0.f;

    for (int it = 0; it < fullIters; ++it) {
        // 4 labels + 4 feature float4s, all imm-offset from two pointers
        const int lab0 = lp[0];
        const int lab1 = lp[1];
        const int lab2 = lp[2];
        const int lab3 = lp[3];
        const f32x4 v0 = *(const f32x4*)(p);
        const f32x4 v1 = *(const f32x4*)(p + D);
        const f32x4 v2 = *(const f32x4*)(p + 2 * D);
        const f32x4 v3 = *(const f32x4*)(p + 3 * D);

        const float m10 = (lab0 == 1) ? 1.0f : 0.0f;
        const float m20 = (lab0 == 2) ? 1.0f : 0.0f;
        const float m11 = (lab1 == 1) ? 1.0f : 0.0f;
        const float m21 = (lab1 == 2) ? 1.0f : 0.0f;
        const float m12 = (lab2 == 1) ? 1.0f : 0.0f;
        const float m22 = (lab2 == 2) ? 1.0f : 0.0f;
        const float m13 = (lab3 == 1) ? 1.0f : 0.0f;
        const float m23 = (lab3 == 2) ? 1.0f : 0.0f;

        aAll += v0 + v1 + v2 + v3;
        a1 += v0 * m10 + v1 * m11 + v2 * m12 + v3 * m13;
        a2 += v0 * m20 + v1 * m21 + v2 * m22 + v3 * m23;
        c1f += m10 + m11 + m12 + m13;
        c2f += m20 + m21 + m22 + m23;

        p += pStep;
        lp += rowsPerIter;
    }

    // tail: at most one partial iteration with per-row validity
    {
        const long long rt = (long long)fullIters * rowsPerIter + row0;
        if (rt < N) {
            #pragma unroll
            for (int u = 0; u < 4; u++) {
                const long long r = rt + u;
                const bool ok = r < N;
                const long long rc = ok ? r : (N - 1);
                const int lab = labels[rc];
                const f32x4 v = *(const f32x4*)(feat + rc * D + col4 * 4);
                const float okf = ok ? 1.0f : 0.0f;
                const float m1 = (lab == 1) ? okf : 0.0f;
                const float m2 = (lab == 2) ? okf : 0.0f;
                aAll += v * okf;
                a1 += v * m1;
                a2 += v * m2;
                c1f += m1; c2f += m2;
            }
        }
    }

    // block-level reduce into LDS
    const int cbase = col4 * 4;
    #pragma unroll
    for (int j = 0; j < 4; j++) {
        atomicAdd(&s_sum[0 * D + cbase + j], aAll[j]);
        atomicAdd(&s_sum[1 * D + cbase + j], a1[j]);
        atomicAdd(&s_sum[2 * D + cbase + j], a2[j]);
    }
    if (col4 == 0) {  // one counting thread per row-group
        atomicAdd(&s_cnt[0], c1f);
        atomicAdd(&s_cnt[1], c2f);
    }
    __syncthreads();

    // one global atomic per element per block, into this block's replica
    float* msums = sums + (blockIdx.x & (REP - 1)) * NCLS * D;
    float* mcnt = counts + (blockIdx.x & (REP - 1)) * 2;
    for (int i = t; i < NCLS * D; i += 256) atomicAdd(&msums[i], s_sum[i]);
    if (t < 2) atomicAdd(&mcnt[t], s_cnt[t]);
}

__global__ __launch_bounds__(128) void finalize_kernel(
    const float* __restrict__ sums, const float* __restrict__ counts,
    float* __restrict__ out, int tail, int N)
{
    __shared__ float s_red[NCLS][2];
    const int t = threadIdx.x;           // 128 threads, one per column
    const int lane = t & 63;
    const int wv = t >> 6;

    float cnt1 = 0.f, cnt2 = 0.f;
    float sAll = 0.f, s1 = 0.f, s2 = 0.f;
    #pragma unroll
    for (int rp = 0; rp < REP; rp++) {
        cnt1 += counts[rp * 2 + 0];
        cnt2 += counts[rp * 2 + 1];
        sAll += sums[rp * NCLS * D + 0 * D + t];
        s1   += sums[rp * NCLS * D + 1 * D + t];
        s2   += sums[rp * NCLS * D + 2 * D + t];
    }
    const float cnt0 = (float)N - cnt1 - cnt2;

    float center[NCLS];
    center[0] = (sAll - s1 - s2) / cnt0;
    center[1] = s1 / cnt1;
    center[2] = s2 / cnt2;

    #pragma unroll
    for (int k = 0; k < NCLS; k++) {
        float sq = center[k] * center[k];
        #pragma unroll
        for (int off = 32; off > 0; off >>= 1) sq += __shfl_down(sq, off, 64);
        if (lane == 0) s_red[k][wv] = sq;
    }
    __syncthreads();

    #pragma unroll
    for (int k = 0; k < NCLS; k++) {
        const float norm = sqrtf(s_red[k][0] + s_red[k][1]);
        out[k * D + t] = center[k] / fmaxf(norm, 1e-12f);
    }
    // second tuple output: target = arange(NUM_CLASSES), stored as output dtype
    if (t < tail) out[NCLS * D + t] = (float)t;
}

extern "C" void kernel_launch(void* const* d_in, const int* in_sizes, int n_in,
                              void* d_out, int out_size, void* d_ws, size_t ws_size,
                              hipStream_t stream) {
    const float* feat = (const float*)d_in[0];
    const int* labels = (const int*)d_in[1];
    const int N = in_sizes[1];

    float* sums = (float*)d_ws;
    float* counts = (float*)d_ws + REP * NCLS * D;

    // zero the accumulator workspace every call (harness poisons ws once, never restores)
    hipMemsetAsync(d_ws, 0, (REP * NCLS * D + REP * 2) * sizeof(float), stream);

    const int grid = 2048;
    const int rowsPerIter = grid * 32;
    const int fullIters = N / rowsPerIter;

    class_sum_kernel<<<grid, 256, 0, stream>>>(feat, labels, sums, counts, N, fullIters);

    int tail = out_size - NCLS * D;
    if (tail < 0) tail = 0;
    if (tail > D) tail = D;
    finalize_kernel<<<1, 128, 0, stream>>>(sums, counts, (float*)d_out, tail, N);
}

// Round 7
// 62.173 us; speedup vs baseline: 1.0857x; 1.0857x over previous
//
#include <hip/hip_runtime.h>

#define D 128
#define NCLS 3
#define REP 8

typedef float f32x4 __attribute__((ext_vector_type(4)));
typedef int   i32x4 __attribute__((ext_vector_type(4)));

// ws layout (floats): [0 .. REP*384-1] per-class sums (REP replicas of {all,c1,c2} x 128),
//                     [REP*384 .. REP*384+REP*2-1] float counts of class1/class2

__global__ __launch_bounds__(256, 4) void class_sum_kernel(
    const float* __restrict__ feat, const int* __restrict__ labels,
    float* __restrict__ sums, float* __restrict__ counts, int N, int fullIters)
{
    __shared__ float s_sum[NCLS * D];   // rows: 0=all, 1=class1, 2=class2
    __shared__ float s_cnt[2];
    const int t = threadIdx.x;

    for (int i = t; i < NCLS * D; i += 256) s_sum[i] = 0.0f;
    if (t < 2) s_cnt[t] = 0.0f;
    __syncthreads();

    const int col4 = t & 31;          // float4 slot within the 128-wide row
    const int rgrp = t >> 5;          // 0..7 -> this thread's 8-row group
    const int row0 = blockIdx.x * 64 + rgrp * 8;
    const int rowsPerIter = gridDim.x * 64;

    const float* __restrict__ p = feat + (size_t)row0 * D + col4 * 4;
    const int* __restrict__ lp = labels + row0;
    const size_t pStep = (size_t)rowsPerIter * D;

    const f32x4 z = {0.f, 0.f, 0.f, 0.f};
    f32x4 aAll = z, a1 = z, a2 = z;
    float c1f = 0.f, c2f = 0.f;

    for (int it = 0; it < fullIters; ++it) {
        // 2 label int4 loads + 8 feature float4 loads, all imm-offset
        const i32x4 lA = *(const i32x4*)(lp);
        const i32x4 lB = *(const i32x4*)(lp + 4);
        f32x4 v[8];
        #pragma unroll
        for (int u = 0; u < 8; u++) v[u] = *(const f32x4*)(p + u * D);

        #pragma unroll
        for (int u = 0; u < 8; u++) {
            const int lab = (u < 4) ? lA[u & 3] : lB[u & 3];
            const float m1 = (lab == 1) ? 1.0f : 0.0f;
            const float m2 = (lab == 2) ? 1.0f : 0.0f;
            aAll += v[u];
            a1 += v[u] * m1;
            a2 += v[u] * m2;
            c1f += m1;
            c2f += m2;
        }

        p += pStep;
        lp += rowsPerIter;
    }

    // tail: at most one partial iteration with per-row validity
    {
        const long long rt = (long long)fullIters * rowsPerIter + row0;
        if (rt < N) {
            #pragma unroll
            for (int u = 0; u < 8; u++) {
                const long long r = rt + u;
                const bool ok = r < N;
                const long long rc = ok ? r : (N - 1);
                const int lab = labels[rc];
                const f32x4 v = *(const f32x4*)(feat + rc * D + col4 * 4);
                const float okf = ok ? 1.0f : 0.0f;
                const float m1 = (lab == 1) ? okf : 0.0f;
                const float m2 = (lab == 2) ? okf : 0.0f;
                aAll += v * okf;
                a1 += v * m1;
                a2 += v * m2;
                c1f += m1; c2f += m2;
            }
        }
    }

    // block-level reduce into LDS
    const int cbase = col4 * 4;
    #pragma unroll
    for (int j = 0; j < 4; j++) {
        atomicAdd(&s_sum[0 * D + cbase + j], aAll[j]);
        atomicAdd(&s_sum[1 * D + cbase + j], a1[j]);
        atomicAdd(&s_sum[2 * D + cbase + j], a2[j]);
    }
    if (col4 == 0) {  // one counting thread per row-group
        atomicAdd(&s_cnt[0], c1f);
        atomicAdd(&s_cnt[1], c2f);
    }
    __syncthreads();

    // one global atomic per element per block, into this block's replica
    float* msums = sums + (blockIdx.x & (REP - 1)) * NCLS * D;
    float* mcnt = counts + (blockIdx.x & (REP - 1)) * 2;
    for (int i = t; i < NCLS * D; i += 256) atomicAdd(&msums[i], s_sum[i]);
    if (t < 2) atomicAdd(&mcnt[t], s_cnt[t]);
}

__global__ __launch_bounds__(128) void finalize_kernel(
    const float* __restrict__ sums, const float* __restrict__ counts,
    float* __restrict__ out, int tail, int N)
{
    __shared__ float s_red[NCLS][2];
    const int t = threadIdx.x;           // 128 threads, one per column
    const int lane = t & 63;
    const int wv = t >> 6;

    float cnt1 = 0.f, cnt2 = 0.f;
    float sAll = 0.f, s1 = 0.f, s2 = 0.f;
    #pragma unroll
    for (int rp = 0; rp < REP; rp++) {
        cnt1 += counts[rp * 2 + 0];
        cnt2 += counts[rp * 2 + 1];
        sAll += sums[rp * NCLS * D + 0 * D + t];
        s1   += sums[rp * NCLS * D + 1 * D + t];
        s2   += sums[rp * NCLS * D + 2 * D + t];
    }
    const float cnt0 = (float)N - cnt1 - cnt2;

    float center[NCLS];
    center[0] = (sAll - s1 - s2) / cnt0;
    center[1] = s1 / cnt1;
    center[2] = s2 / cnt2;

    #pragma unroll
    for (int k = 0; k < NCLS; k++) {
        float sq = center[k] * center[k];
        #pragma unroll
        for (int off = 32; off > 0; off >>= 1) sq += __shfl_down(sq, off, 64);
        if (lane == 0) s_red[k][wv] = sq;
    }
    __syncthreads();

    #pragma unroll
    for (int k = 0; k < NCLS; k++) {
        const float norm = sqrtf(s_red[k][0] + s_red[k][1]);
        out[k * D + t] = center[k] / fmaxf(norm, 1e-12f);
    }
    // second tuple output: target = arange(NUM_CLASSES), stored as output dtype
    if (t < tail) out[NCLS * D + t] = (float)t;
}

extern "C" void kernel_launch(void* const* d_in, const int* in_sizes, int n_in,
                              void* d_out, int out_size, void* d_ws, size_t ws_size,
                              hipStream_t stream) {
    const float* feat = (const float*)d_in[0];
    const int* labels = (const int*)d_in[1];
    const int N = in_sizes[1];

    float* sums = (float*)d_ws;
    float* counts = (float*)d_ws + REP * NCLS * D;

    // zero the accumulator workspace every call (harness poisons ws once, never restores)
    hipMemsetAsync(d_ws, 0, (REP * NCLS * D + REP * 2) * sizeof(float), stream);

    const int grid = 1024;
    const int rowsPerIter = grid * 64;
    const int fullIters = N / rowsPerIter;

    class_sum_kernel<<<grid, 256, 0, stream>>>(feat, labels, sums, counts, N, fullIters);

    int tail = out_size - NCLS * D;
    if (tail < 0) tail = 0;
    if (tail > D) tail = D;
    finalize_kernel<<<1, 128, 0, stream>>>(sums, counts, (float*)d_out, tail, N);
}

// Round 8
// 58.820 us; speedup vs baseline: 1.1476x; 1.0570x over previous
//
#include <hip/hip_runtime.h>

#define D 128
#define NCLS 3
#define REP 8

typedef float f32x4 __attribute__((ext_vector_type(4)));
typedef int   i32x4 __attribute__((ext_vector_type(4)));

// ws layout (floats): [0 .. REP*384-1] per-class sums (REP replicas of {all,c1,c2} x 128),
//                     [REP*384 .. REP*384+REP*2-1] float counts of class1/class2

__global__ __launch_bounds__(256, 5) void class_sum_kernel(
    const float* __restrict__ feat, const int* __restrict__ labels,
    float* __restrict__ sums, float* __restrict__ counts, int N, int fullIters)
{
    __shared__ float s_sum[NCLS * D];   // rows: 0=all, 1=class1, 2=class2
    __shared__ float s_cnt[2];
    const int t = threadIdx.x;

    for (int i = t; i < NCLS * D; i += 256) s_sum[i] = 0.0f;
    if (t < 2) s_cnt[t] = 0.0f;
    __syncthreads();

    const int col4 = t & 31;          // float4 slot within the 128-wide row
    const int rgrp = t >> 5;          // 0..7 -> this thread's 8-row group
    const int row0 = blockIdx.x * 64 + rgrp * 8;
    const int rowsPerIter = gridDim.x * 64;

    const float* __restrict__ p = feat + (size_t)row0 * D + col4 * 4;
    const int* __restrict__ lp = labels + row0;
    const size_t pStep = (size_t)rowsPerIter * D;

    const f32x4 z = {0.f, 0.f, 0.f, 0.f};
    f32x4 aAll = z, a1 = z, a2 = z;
    float c1f = 0.f, c2f = 0.f;

    for (int it = 0; it < fullIters; ++it) {
        // 2 label int4 loads + 8 feature float4 loads, all imm-offset
        const i32x4 lA = *(const i32x4*)(lp);
        const i32x4 lB = *(const i32x4*)(lp + 4);
        f32x4 v[8];
        #pragma unroll
        for (int u = 0; u < 8; u++) v[u] = *(const f32x4*)(p + u * D);

        #pragma unroll
        for (int u = 0; u < 8; u++) {
            const int lab = (u < 4) ? lA[u & 3] : lB[u & 3];
            const float m1 = (lab == 1) ? 1.0f : 0.0f;
            const float m2 = (lab == 2) ? 1.0f : 0.0f;
            aAll += v[u];
            a1 += v[u] * m1;
            a2 += v[u] * m2;
            c1f += m1;
            c2f += m2;
        }

        p += pStep;
        lp += rowsPerIter;
    }

    // tail: at most one partial iteration with per-row validity
    {
        const long long rt = (long long)fullIters * rowsPerIter + row0;
        if (rt < N) {
            #pragma unroll
            for (int u = 0; u < 8; u++) {
                const long long r = rt + u;
                const bool ok = r < N;
                const long long rc = ok ? r : (N - 1);
                const int lab = labels[rc];
                const f32x4 v = *(const f32x4*)(feat + rc * D + col4 * 4);
                const float okf = ok ? 1.0f : 0.0f;
                const float m1 = (lab == 1) ? okf : 0.0f;
                const float m2 = (lab == 2) ? okf : 0.0f;
                aAll += v * okf;
                a1 += v * m1;
                a2 += v * m2;
                c1f += m1; c2f += m2;
            }
        }
    }

    // block-level reduce into LDS
    const int cbase = col4 * 4;
    #pragma unroll
    for (int j = 0; j < 4; j++) {
        atomicAdd(&s_sum[0 * D + cbase + j], aAll[j]);
        atomicAdd(&s_sum[1 * D + cbase + j], a1[j]);
        atomicAdd(&s_sum[2 * D + cbase + j], a2[j]);
    }
    if (col4 == 0) {  // one counting thread per row-group
        atomicAdd(&s_cnt[0], c1f);
        atomicAdd(&s_cnt[1], c2f);
    }
    __syncthreads();

    // one global atomic per element per block, into this block's replica
    float* msums = sums + (blockIdx.x & (REP - 1)) * NCLS * D;
    float* mcnt = counts + (blockIdx.x & (REP - 1)) * 2;
    for (int i = t; i < NCLS * D; i += 256) atomicAdd(&msums[i], s_sum[i]);
    if (t < 2) atomicAdd(&mcnt[t], s_cnt[t]);
}

__global__ __launch_bounds__(128) void finalize_kernel(
    const float* __restrict__ sums, const float* __restrict__ counts,
    float* __restrict__ out, int tail, int N)
{
    __shared__ float s_red[NCLS][2];
    const int t = threadIdx.x;           // 128 threads, one per column
    const int lane = t & 63;
    const int wv = t >> 6;

    float cnt1 = 0.f, cnt2 = 0.f;
    float sAll = 0.f, s1 = 0.f, s2 = 0.f;
    #pragma unroll
    for (int rp = 0; rp < REP; rp++) {
        cnt1 += counts[rp * 2 + 0];
        cnt2 += counts[rp * 2 + 1];
        sAll += sums[rp * NCLS * D + 0 * D + t];
        s1   += sums[rp * NCLS * D + 1 * D + t];
        s2   += sums[rp * NCLS * D + 2 * D + t];
    }
    const float cnt0 = (float)N - cnt1 - cnt2;

    float center[NCLS];
    center[0] = (sAll - s1 - s2) / cnt0;
    center[1] = s1 / cnt1;
    center[2] = s2 / cnt2;

    #pragma unroll
    for (int k = 0; k < NCLS; k++) {
        float sq = center[k] * center[k];
        #pragma unroll
        for (int off = 32; off > 0; off >>= 1) sq += __shfl_down(sq, off, 64);
        if (lane == 0) s_red[k][wv] = sq;
    }
    __syncthreads();

    #pragma unroll
    for (int k = 0; k < NCLS; k++) {
        const float norm = sqrtf(s_red[k][0] + s_red[k][1]);
        out[k * D + t] = center[k] / fmaxf(norm, 1e-12f);
    }
    // second tuple output: target = arange(NUM_CLASSES), stored as output dtype
    if (t < tail) out[NCLS * D + t] = (float)t;
}

extern "C" void kernel_launch(void* const* d_in, const int* in_sizes, int n_in,
                              void* d_out, int out_size, void* d_ws, size_t ws_size,
                              hipStream_t stream) {
    const float* feat = (const float*)d_in[0];
    const int* labels = (const int*)d_in[1];
    const int N = in_sizes[1];

    float* sums = (float*)d_ws;
    float* counts = (float*)d_ws + REP * NCLS * D;

    // zero the accumulator workspace every call (harness poisons ws once, never restores)
    hipMemsetAsync(d_ws, 0, (REP * NCLS * D + REP * 2) * sizeof(float), stream);

    const int grid = 1280;   // exactly 5 blocks/CU; launch_bounds(256,5) keeps all resident
    const int rowsPerIter = grid * 64;
    const int fullIters = N / rowsPerIter;

    class_sum_kernel<<<grid, 256, 0, stream>>>(feat, labels, sums, counts, N, fullIters);

    int tail = out_size - NCLS * D;
    if (tail < 0) tail = 0;
    if (tail > D) tail = D;
    finalize_kernel<<<1, 128, 0, stream>>>(sums, counts, (float*)d_out, tail, N);
}